// Round 1
// baseline (107.246 us; speedup 1.0000x reference)
//
#include <hip/hip_runtime.h>
#include <math.h>

#ifndef __has_builtin
#define __has_builtin(x) 0
#endif

__device__ __forceinline__ float fast_exp2(float x) {
#if __has_builtin(__builtin_amdgcn_exp2f)
    return __builtin_amdgcn_exp2f(x);   // raw v_exp_f32
#else
    return exp2f(x);
#endif
}

// ---------------------------------------------------------------------------
// Kernel 1: pack per-node constants: {px, py, s, w0, w1, w2, 0, 0} (32 B/node)
// s = -log2(e) / (2 * sigmaSq)  so that rbf = exp2(Dsq * s) == exp(-Dsq/(2 s2))
// ---------------------------------------------------------------------------
__global__ void pack_nodes(const int* __restrict__ pat, const float* __restrict__ W2,
                           const float* __restrict__ sigmaSq, float* __restrict__ nodes,
                           int P) {
    int p = blockIdx.x * blockDim.x + threadIdx.x;
    if (p >= P) return;
    float* q = nodes + 8 * (size_t)p;
    q[0] = (float)pat[2 * p];
    q[1] = (float)pat[2 * p + 1];
    q[2] = -0.7213475204444817f / sigmaSq[p];   // -log2(e)/2 / sigma^2
    q[3] = W2[p];            // W2 is (C,P) row-major
    q[4] = W2[P + p];
    q[5] = W2[2 * P + p];
    q[6] = 0.0f;
    q[7] = 0.0f;
}

// ---------------------------------------------------------------------------
// Kernel 2: main RBF loop. One thread per query n; loops over a P-chunk with a
// wave-uniform index so node data comes in via s_load (scalar pipe).
// SPLIT=true: write float4 partials {den, a0, a1, a2} to ws.
// SPLIT=false: finalize directly to out.
// ---------------------------------------------------------------------------
template <int PCHUNK, bool SPLIT>
__global__ __launch_bounds__(256) void rbf_main(const int* __restrict__ X,
                                                const float* __restrict__ nodes,
                                                float* __restrict__ outp, int N) {
    int n = blockIdx.x * 256 + threadIdx.x;
    int pc = SPLIT ? blockIdx.y : 0;
    const float* __restrict__ q = nodes + (size_t)pc * PCHUNK * 8;

    int2 xi = ((const int2*)X)[n];
    float xn = (float)xi.x, yn = (float)xi.y;

    float den = 0.f, a0 = 0.f, a1 = 0.f, a2 = 0.f;
#pragma unroll 8
    for (int j = 0; j < PCHUNK; ++j) {
        float px = q[j * 8 + 0];
        float py = q[j * 8 + 1];
        float s  = q[j * 8 + 2];
        float w0 = q[j * 8 + 3];
        float w1 = q[j * 8 + 4];
        float w2 = q[j * 8 + 5];
        float dx = xn - px;
        float dy = yn - py;
        float r  = fast_exp2(fmaf(dy, dy, dx * dx) * s);
        den += r;
        a0 = fmaf(r, w0, a0);
        a1 = fmaf(r, w1, a1);
        a2 = fmaf(r, w2, a2);
    }

    if (SPLIT) {
        float4 v;
        v.x = den; v.y = a0; v.z = a1; v.w = a2;
        ((float4*)outp)[(size_t)pc * N + n] = v;
    } else {
        outp[3 * n + 0] = a0 / den;
        outp[3 * n + 1] = a1 / den;
        outp[3 * n + 2] = a2 / den;
    }
}

// Generic (runtime-P) fallback, non-split — only used if sizes are unexpected.
__global__ __launch_bounds__(256) void rbf_main_dyn(const int* __restrict__ X,
                                                    const float* __restrict__ nodes,
                                                    float* __restrict__ outp,
                                                    int N, int P) {
    int n = blockIdx.x * 256 + threadIdx.x;
    if (n >= N) return;
    float xn = (float)X[2 * n], yn = (float)X[2 * n + 1];
    float den = 0.f, a0 = 0.f, a1 = 0.f, a2 = 0.f;
    for (int j = 0; j < P; ++j) {
        const float* q = nodes + (size_t)j * 8;
        float dx = xn - q[0], dy = yn - q[1];
        float r = fast_exp2(fmaf(dy, dy, dx * dx) * q[2]);
        den += r;
        a0 = fmaf(r, q[3], a0);
        a1 = fmaf(r, q[4], a1);
        a2 = fmaf(r, q[5], a2);
    }
    outp[3 * n + 0] = a0 / den;
    outp[3 * n + 1] = a1 / den;
    outp[3 * n + 2] = a2 / den;
}

// ---------------------------------------------------------------------------
// Kernel 3: reduce the PSPLIT partials and divide.
// ---------------------------------------------------------------------------
__global__ __launch_bounds__(256) void rbf_reduce(const float* __restrict__ part,
                                                  float* __restrict__ out,
                                                  int N, int psplit) {
    int n = blockIdx.x * 256 + threadIdx.x;
    if (n >= N) return;
    float den = 0.f, a0 = 0.f, a1 = 0.f, a2 = 0.f;
    for (int pc = 0; pc < psplit; ++pc) {
        float4 v = ((const float4*)part)[(size_t)pc * N + n];
        den += v.x; a0 += v.y; a1 += v.z; a2 += v.w;
    }
    out[3 * n + 0] = a0 / den;
    out[3 * n + 1] = a1 / den;
    out[3 * n + 2] = a2 / den;
}

extern "C" void kernel_launch(void* const* d_in, const int* in_sizes, int n_in,
                              void* d_out, int out_size, void* d_ws, size_t ws_size,
                              hipStream_t stream) {
    const int*   X    = (const int*)d_in[0];
    const int*   pat  = (const int*)d_in[1];
    const float* W2   = (const float*)d_in[2];
    const float* sig  = (const float*)d_in[3];
    float*       out  = (float*)d_out;

    const int N = in_sizes[0] / 2;     // 65536
    const int P = in_sizes[3];         // 2048

    float* nodes = (float*)d_ws;
    size_t nodes_bytes = (size_t)P * 8 * sizeof(float);

    pack_nodes<<<dim3((P + 255) / 256), dim3(256), 0, stream>>>(pat, W2, sig, nodes, P);

    const int PSPLIT = 8;
    const int PCHUNK = 256;            // P / PSPLIT
    size_t part_bytes = (size_t)PSPLIT * N * 4 * sizeof(float);

    bool fast_path = (P == PSPLIT * PCHUNK) && (N % 256 == 0) &&
                     (ws_size >= nodes_bytes + part_bytes);

    if (fast_path) {
        float* part = nodes + (size_t)P * 8;   // 64 KB in, 16 B aligned
        dim3 grid(N / 256, PSPLIT);
        rbf_main<PCHUNK, true><<<grid, dim3(256), 0, stream>>>(X, nodes, part, N);
        rbf_reduce<<<dim3(N / 256), dim3(256), 0, stream>>>(part, out, N, PSPLIT);
    } else if (P == 2048 && N % 256 == 0) {
        rbf_main<2048, false><<<dim3(N / 256), dim3(256), 0, stream>>>(X, nodes, out, N);
    } else {
        rbf_main_dyn<<<dim3((N + 255) / 256), dim3(256), 0, stream>>>(X, nodes, out, N, P);
    }
}